// Round 4
// baseline (788.638 us; speedup 1.0000x reference)
//
#include <hip/hip_runtime.h>

typedef __bf16 bf16;
typedef __bf16 bf16x8 __attribute__((ext_vector_type(8)));
typedef __bf16 bf16x4 __attribute__((ext_vector_type(4)));
typedef float  f32x4  __attribute__((ext_vector_type(4)));

#define B_   2
#define S_   4096
#define HID_ 2048
#define H_   16
#define D_   128
#define C_   256
#define NC_  16
#define M_   (B_*S_)   // 8192 rows
#define K_   2048      // inner dim of both big GEMMs

typedef __attribute__((address_space(1))) const void gas_t;
typedef __attribute__((address_space(3))) void las_t;

// ---------------------------------------------------------------------------
// Fused convert: blocks [0,8192) do f32->bf16 of x (8 elems/thread);
// blocks [8192,28672) transpose-convert weights to bf16 [N][K]:
// rows 0..6143 = w_qkv cols, 6144..8191 = w_gate cols, 8192..10239 = w_out.
// ---------------------------------------------------------------------------
__global__ void cvt_kernel(const float* __restrict__ x,
                           const float* __restrict__ wqkv,
                           const float* __restrict__ wgate,
                           const float* __restrict__ wout,
                           bf16* __restrict__ xb, bf16* __restrict__ wT) {
    __shared__ float tile[32][33];
    int bid = blockIdx.x, tid = threadIdx.x;
    if (bid < 8192) {
        int idx = (bid * 256 + tid) * 8;
        float4 f0 = *(const float4*)(x + idx);
        float4 f1 = *(const float4*)(x + idx + 4);
        bf16x8 o;
        o[0] = (bf16)f0.x; o[1] = (bf16)f0.y; o[2] = (bf16)f0.z; o[3] = (bf16)f0.w;
        o[4] = (bf16)f1.x; o[5] = (bf16)f1.y; o[6] = (bf16)f1.z; o[7] = (bf16)f1.w;
        *(bf16x8*)(xb + idx) = o;
        return;
    }
    bid -= 8192;
    int k0 = (bid & 63) * 32, n0 = (bid >> 6) * 32;
    const float* src; int ld, col0;
    if (n0 < 6144)      { src = wqkv;  ld = 6144; col0 = n0; }
    else if (n0 < 8192) { src = wgate; ld = 2048; col0 = n0 - 6144; }
    else                { src = wout;  ld = 2048; col0 = n0 - 8192; }
    int tx = tid & 31, ty = tid >> 5;
#pragma unroll
    for (int i = 0; i < 4; i++) {
        int kk = ty + i * 8;
        tile[kk][tx] = src[(size_t)(k0 + kk) * ld + col0 + tx];
    }
    __syncthreads();
#pragma unroll
    for (int i = 0; i < 4; i++) {
        int nn = ty + i * 8;
        wT[(size_t)(n0 + nn) * K_ + k0 + tx] = (bf16)tile[tx][nn];
    }
}

// ---------------------------------------------------------------------------
// bf16 GEMM, C[M][N] = act( A[M][K] @ B[N][K]^T ).  128x128 tile, 4 waves
// (2x2 of 64x64), BK=32, mfma 16x16x32 bf16, global_load_lds width=16.
// LDS layout XOR-swizzled: slot(row,q) = q ^ ((row>>1)&3) so ds_read_b128
// fragment reads are <=2-way (free).  Staging thread tid fetches global
// colblock (tid&3)^((tid>>3)&3) -> same 64B segment, coalescing preserved.
// MODE 0: N=8192, split output into q/k/v (silu) and gate (sigmoid), bf16.
// MODE 1: N=2048, plain f32 output to d_out.
// ---------------------------------------------------------------------------
template <int MODE>
__global__ __launch_bounds__(256) void gemm_kernel(
        const bf16* __restrict__ A, const bf16* __restrict__ Bm,
        bf16* __restrict__ qo, bf16* __restrict__ ko,
        bf16* __restrict__ vo, bf16* __restrict__ go,
        float* __restrict__ out) {
    __shared__ __align__(16) bf16 As[128 * 32];
    __shared__ __align__(16) bf16 Bs[128 * 32];
    const int m0 = blockIdx.x * 128, n0 = blockIdx.y * 128;
    const int tid = threadIdx.x, lane = tid & 63, wid = tid >> 6;
    const int quad = lane >> 4, l15 = lane & 15;
    const int i0w = (wid >> 1) * 64, j0w = (wid & 1) * 64;
    f32x4 acc[4][4] = {};
    // staging: thread tid -> row tid>>2, swizzled colblock
    const int srow = tid >> 2;
    const int sq = (tid & 3) ^ ((tid >> 3) & 3);
    const bf16* Ag = A  + (size_t)(m0 + srow) * K_ + sq * 8;
    const bf16* Bg = Bm + (size_t)(n0 + srow) * K_ + sq * 8;
    const size_t rowskip = (size_t)64 * K_;
    bf16* AsDst = As + tid * 8;
    bf16* BsDst = Bs + tid * 8;
    // fragment read slot (loop-invariant)
    const int slot = quad ^ ((l15 >> 1) & 3);

    for (int kb = 0; kb < K_; kb += 32) {
        __builtin_amdgcn_global_load_lds((gas_t*)(Ag + kb),           (las_t*)AsDst,          16, 0, 0);
        __builtin_amdgcn_global_load_lds((gas_t*)(Ag + kb + rowskip), (las_t*)(AsDst + 2048), 16, 0, 0);
        __builtin_amdgcn_global_load_lds((gas_t*)(Bg + kb),           (las_t*)BsDst,          16, 0, 0);
        __builtin_amdgcn_global_load_lds((gas_t*)(Bg + kb + rowskip), (las_t*)(BsDst + 2048), 16, 0, 0);
        __syncthreads();
        bf16x8 af[4], bfr[4];
#pragma unroll
        for (int t = 0; t < 4; t++)
            af[t] = *(const bf16x8*)&As[(i0w + t * 16 + l15) * 32 + slot * 8];
#pragma unroll
        for (int t = 0; t < 4; t++)
            bfr[t] = *(const bf16x8*)&Bs[(j0w + t * 16 + l15) * 32 + slot * 8];
#pragma unroll
        for (int ti = 0; ti < 4; ti++)
#pragma unroll
            for (int tj = 0; tj < 4; tj++)
                acc[ti][tj] = __builtin_amdgcn_mfma_f32_16x16x32_bf16(
                    af[ti], bfr[tj], acc[ti][tj], 0, 0, 0);
        __syncthreads();
    }

    if (MODE == 0) {
        bf16* outb = (n0 < 2048) ? qo : (n0 < 4096) ? ko : (n0 < 6144) ? vo : go;
        const bool silu = (n0 < 6144);
        const int cb = n0 & 2047;
#pragma unroll
        for (int ti = 0; ti < 4; ti++)
#pragma unroll
            for (int tj = 0; tj < 4; tj++)
#pragma unroll
                for (int r = 0; r < 4; r++) {
                    int row = m0 + i0w + ti * 16 + quad * 4 + r;
                    int col = cb + j0w + tj * 16 + l15;
                    float xv = acc[ti][tj][r];
                    float sg = 1.f / (1.f + __expf(-xv));
                    float av = silu ? xv * sg : sg;
                    outb[(size_t)row * 2048 + col] = (bf16)av;
                }
    } else {
#pragma unroll
        for (int ti = 0; ti < 4; ti++)
#pragma unroll
            for (int tj = 0; tj < 4; tj++)
#pragma unroll
                for (int r = 0; r < 4; r++) {
                    int row = m0 + i0w + ti * 16 + quad * 4 + r;
                    int col = n0 + j0w + tj * 16 + l15;
                    out[(size_t)row * 2048 + col] = acc[ti][tj][r];
                }
    }
}

// ---------------------------------------------------------------------------
// Transpose k and v per (b,h): [S][D] -> [D][S]   (bf16, LDS 64x64 tiles)
// grid (S/64, D/64, 2*32): z = arr*32 + bh.
// The k copy (arr==0) is pre-scaled by k_decay[j] = exp(-s*(255 - j%256)),
// which depends only on tx -> one __expf per thread.  kT feeds only pass_a.
// ---------------------------------------------------------------------------
__global__ void transpose_kernel(const bf16* __restrict__ kin,
                                 const bf16* __restrict__ vin,
                                 const float* __restrict__ slopes,
                                 bf16* __restrict__ kT, bf16* __restrict__ vT) {
    __shared__ bf16 tile[64][65];
    int x0 = blockIdx.x * 64, d0 = blockIdx.y * 64;
    int z = blockIdx.z, arr = z >> 5, bh = z & 31, b = bh >> 4, h = bh & 15;
    const bf16* src = arr ? vin : kin;
    bf16* dst = arr ? vT : kT;
    int tx = threadIdx.x, ty = threadIdx.y;
    float fscale = 1.f;
    if (arr == 0)
        fscale = __expf(-slopes[h] * (float)(255 - ((x0 + tx) & 255)));
#pragma unroll
    for (int r = 0; r < 16; r++) {
        int lr = ty * 16 + r;
        tile[lr][tx] = src[(size_t)(b * S_ + x0 + lr) * 2048 + h * 128 + d0 + tx];
    }
    __syncthreads();
#pragma unroll
    for (int r = 0; r < 16; r++) {
        int lr = ty * 16 + r;
        dst[(size_t)(bh * 128 + d0 + lr) * S_ + x0 + tx] =
            (bf16)((float)tile[tx][lr] * fscale);
    }
}

// ---------------------------------------------------------------------------
// Pass A: per (chunk c, b, h) KV^T[e][d] = sum_j vT[e][j] * kT_scaled[d][j].
// M=N=128, K=256.  Pure load+MFMA (decay pre-folded into kT).
// ---------------------------------------------------------------------------
__global__ __launch_bounds__(256) void pass_a_kernel(
        const bf16* __restrict__ kT, const bf16* __restrict__ vT,
        bf16* __restrict__ KVT) {
    int c = blockIdx.x, bh = blockIdx.y;
    int tid = threadIdx.x, lane = tid & 63, wid = tid >> 6;
    int quad = lane >> 4, l15 = lane & 15;
    int e0 = (wid >> 1) * 64, d0 = (wid & 1) * 64;
    const bf16* vb = vT + (size_t)bh * 128 * S_ + c * 256;
    const bf16* kb = kT + (size_t)bh * 128 * S_ + c * 256;
    f32x4 acc[4][4] = {};
    for (int kbs = 0; kbs < 256; kbs += 32) {
        int j0 = kbs + quad * 8;
        bf16x8 af[4], bfr[4];
#pragma unroll
        for (int t = 0; t < 4; t++)
            af[t] = *(const bf16x8*)(vb + (size_t)(e0 + t * 16 + l15) * S_ + j0);
#pragma unroll
        for (int t = 0; t < 4; t++)
            bfr[t] = *(const bf16x8*)(kb + (size_t)(d0 + t * 16 + l15) * S_ + j0);
#pragma unroll
        for (int ti = 0; ti < 4; ti++)
#pragma unroll
            for (int tj = 0; tj < 4; tj++)
                acc[ti][tj] = __builtin_amdgcn_mfma_f32_16x16x32_bf16(
                    af[ti], bfr[tj], acc[ti][tj], 0, 0, 0);
    }
    size_t base = ((size_t)c * 32 + bh) * 16384;
#pragma unroll
    for (int ti = 0; ti < 4; ti++)
#pragma unroll
        for (int tj = 0; tj < 4; tj++)
#pragma unroll
            for (int r = 0; r < 4; r++) {
                int e = e0 + ti * 16 + quad * 4 + r, d = d0 + tj * 16 + l15;
                KVT[base + (size_t)e * 128 + d] = (bf16)acc[ti][tj][r];
            }
}

// ---------------------------------------------------------------------------
// Pass B: decayed prefix scan of KV^T over chunks; stT[c] = state BEFORE c.
// ---------------------------------------------------------------------------
__global__ void scan_kernel(const bf16* __restrict__ KVT,
                            const float* __restrict__ slopes,
                            bf16* __restrict__ stT) {
    int slice = blockIdx.x, bh = blockIdx.y;
    float s = slopes[bh & 15];
    float bd = __expf(-s * 256.f);
    size_t off = (size_t)slice * 1024 + threadIdx.x * 4;
    float kv0 = 0.f, kv1 = 0.f, kv2 = 0.f, kv3 = 0.f;
    for (int c = 0; c < 16; c++) {
        size_t idx = ((size_t)c * 32 + bh) * 16384 + off;
        bf16x4 st;
        st[0] = (bf16)kv0; st[1] = (bf16)kv1; st[2] = (bf16)kv2; st[3] = (bf16)kv3;
        *(bf16x4*)(stT + idx) = st;
        bf16x4 kvc = *(const bf16x4*)(KVT + idx);
        kv0 = bd * kv0 + (float)kvc[0];
        kv1 = bd * kv1 + (float)kvc[1];
        kv2 = bd * kv2 + (float)kvc[2];
        kv3 = bd * kv3 + (float)kvc[3];
    }
}

// ---------------------------------------------------------------------------
// Pass C: o[i][e] = sum_j decay(i,j)(q_i.k_j) v[j][e] + qd[i]*(q_i @ state),
// then * sigmoid gate, bf16 store.
// Wave w owns four interleaved 16-row strips i = ti*64 + w*16 (ti=0..3), so
// the causal skip jt<=ti is perfectly load-balanced (10 tile-iters/wave).
// Inter-chunk q-decay applied as accumulator post-scale (no A-repack).
// P round-trips through per-wave LDS (no barrier needed).
// ---------------------------------------------------------------------------
__global__ __launch_bounds__(256) void pass_c_kernel(
        const bf16* __restrict__ q, const bf16* __restrict__ kk,
        const bf16* __restrict__ vT, const bf16* __restrict__ stT,
        const bf16* __restrict__ gate, const float* __restrict__ slopes,
        bf16* __restrict__ og) {
    __shared__ __align__(16) bf16 P[4][16 * 72];
    __shared__ float dtab[257];
    int c = blockIdx.x, bh = blockIdx.y, b = bh >> 4, h = bh & 15;
    int tid = threadIdx.x, lane = tid & 63, wid = tid >> 6;
    int quad = lane >> 4, l15 = lane & 15;
    float s = slopes[h];
    dtab[tid] = __expf(-s * (float)tid);
    if (tid == 0) dtab[256] = __expf(-s * 256.f);
    __syncthreads();
    const bf16* qb = q  + ((size_t)(b * S_ + c * 256)) * 2048 + h * 128;
    const bf16* kb = kk + ((size_t)(b * S_ + c * 256)) * 2048 + h * 128;
    const bf16* vb = vT + (size_t)bh * 128 * S_ + c * 256;
    const bf16* st = stT + ((size_t)c * 32 + bh) * 16384;
    bf16* Pw = &P[wid][0];
    const int rbase = wid * 16;            // strip offset within each 64-row band
    f32x4 acc[4][8] = {};

    // inter-chunk: q @ stateT rows, K=128 (decay folded in afterwards)
    for (int kbs = 0; kbs < 128; kbs += 32) {
        bf16x8 af[4];
#pragma unroll
        for (int ti = 0; ti < 4; ti++)
            af[ti] = *(const bf16x8*)(qb + (size_t)(ti * 64 + rbase + l15) * 2048 + kbs + quad * 8);
#pragma unroll
        for (int te = 0; te < 8; te++) {
            bf16x8 bfr = *(const bf16x8*)(st + (size_t)(te * 16 + l15) * 128 + kbs + quad * 8);
#pragma unroll
            for (int ti = 0; ti < 4; ti++)
                acc[ti][te] = __builtin_amdgcn_mfma_f32_16x16x32_bf16(
                    af[ti], bfr, acc[ti][te], 0, 0, 0);
        }
    }
    // scale inter result by q_decay(row) = dtab[i+1]
#pragma unroll
    for (int ti = 0; ti < 4; ti++) {
        float qd[4];
#pragma unroll
        for (int r = 0; r < 4; r++) qd[r] = dtab[ti * 64 + rbase + quad * 4 + r + 1];
#pragma unroll
        for (int te = 0; te < 8; te++)
#pragma unroll
            for (int r = 0; r < 4; r++) acc[ti][te][r] *= qd[r];
    }

    // intra-chunk, causal tiles only
#pragma unroll
    for (int ti = 0; ti < 4; ti++) {
        for (int jt = 0; jt <= ti; jt++) {
            f32x4 sacc[4] = {};
            for (int kbs = 0; kbs < 128; kbs += 32) {
                bf16x8 afq = *(const bf16x8*)(qb + (size_t)(ti * 64 + rbase + l15) * 2048 + kbs + quad * 8);
#pragma unroll
                for (int tj = 0; tj < 4; tj++) {
                    bf16x8 bk = *(const bf16x8*)(kb + (size_t)(jt * 64 + tj * 16 + l15) * 2048 + kbs + quad * 8);
                    sacc[tj] = __builtin_amdgcn_mfma_f32_16x16x32_bf16(
                        afq, bk, sacc[tj], 0, 0, 0);
                }
            }
            // causal decay, write P strip (16 rows, wave-private)
#pragma unroll
            for (int tj = 0; tj < 4; tj++)
#pragma unroll
                for (int r = 0; r < 4; r++) {
                    int i = ti * 64 + rbase + quad * 4 + r;
                    int j = jt * 64 + tj * 16 + l15;
                    int diff = i - j;
                    float pv = (diff >= 0) ? sacc[tj][r] * dtab[diff] : 0.f;
                    Pw[(quad * 4 + r) * 72 + tj * 16 + l15] = (bf16)pv;
                }
            // o += P @ vT rows, K=64
#pragma unroll
            for (int k2 = 0; k2 < 64; k2 += 32) {
                bf16x8 afp = *(const bf16x8*)&Pw[l15 * 72 + k2 + quad * 8];
#pragma unroll
                for (int te = 0; te < 8; te++) {
                    bf16x8 bv = *(const bf16x8*)(vb + (size_t)(te * 16 + l15) * S_ + jt * 64 + k2 + quad * 8);
                    acc[ti][te] = __builtin_amdgcn_mfma_f32_16x16x32_bf16(
                        afp, bv, acc[ti][te], 0, 0, 0);
                }
            }
        }
    }

    // epilogue: multiply gate, store bf16
    const bf16* gb = gate + ((size_t)(b * S_ + c * 256)) * 2048 + h * 128;
    bf16* ob = og + ((size_t)(b * S_ + c * 256)) * 2048 + h * 128;
#pragma unroll
    for (int ti = 0; ti < 4; ti++)
#pragma unroll
        for (int te = 0; te < 8; te++)
#pragma unroll
            for (int r = 0; r < 4; r++) {
                int i = ti * 64 + rbase + quad * 4 + r;
                int e = te * 16 + l15;
                float gv = (float)gb[(size_t)i * 2048 + e];
                ob[(size_t)i * 2048 + e] = (bf16)(acc[ti][te][r] * gv);
            }
}

// ---------------------------------------------------------------------------
// Workspace budget (d_ws): 200 MiB.  wT 40 + xb 32 + q/k/v/g 128.
// kT aliases xb (dead after GEMM1).  vT/KVT/stT live in d_out (64 MiB f32),
// all dead before GEMM2 overwrites d_out.
// ---------------------------------------------------------------------------
extern "C" void kernel_launch(void* const* d_in, const int* in_sizes, int n_in,
                              void* d_out, int out_size, void* d_ws, size_t ws_size,
                              hipStream_t stream) {
    const float* x      = (const float*)d_in[0];
    const float* wqkv   = (const float*)d_in[1];
    const float* wgate  = (const float*)d_in[2];
    const float* wout   = (const float*)d_in[3];
    const float* slopes = (const float*)d_in[4];
    float* out = (float*)d_out;

    bf16* wT   = (bf16*)d_ws;                       // [10240][2048]  40 MiB
    bf16* xb   = wT   + (size_t)10240 * 2048;       // [8192][2048]   32 MiB
    bf16* qb   = xb   + (size_t)8192 * 2048;        // 32 MiB
    bf16* kbuf = qb   + (size_t)8192 * 2048;        // 32 MiB
    bf16* vbuf = kbuf + (size_t)8192 * 2048;        // 32 MiB (reused: gated attn)
    bf16* gbuf = vbuf + (size_t)8192 * 2048;        // 32 MiB
    bf16* kT   = xb;                                // alias: xb dead after GEMM1
    bf16* vT   = (bf16*)d_out;                      // [32][128][4096] 32 MiB
    bf16* KVT  = vT + (size_t)32 * 128 * 4096;      // [16][32][128][128] 16 MiB
    bf16* stT  = KVT + (size_t)16 * 32 * 16384;     // 16 MiB  (total = 64 MiB)

    cvt_kernel<<<dim3(28672), dim3(256), 0, stream>>>(x, wqkv, wgate, wout, xb, wT);
    gemm_kernel<0><<<dim3(64, 64), dim3(256), 0, stream>>>(
        xb, wT, qb, kbuf, vbuf, gbuf, (float*)nullptr);
    transpose_kernel<<<dim3(64, 2, 64), dim3(64, 4), 0, stream>>>(
        kbuf, vbuf, slopes, kT, vT);
    pass_a_kernel<<<dim3(16, 32), dim3(256), 0, stream>>>(kT, vT, KVT);
    scan_kernel<<<dim3(16, 32), dim3(256), 0, stream>>>(KVT, slopes, stT);
    pass_c_kernel<<<dim3(16, 32), dim3(256), 0, stream>>>(
        qb, kbuf, vT, stT, gbuf, slopes, vbuf);
    gemm_kernel<1><<<dim3(64, 16), dim3(256), 0, stream>>>(
        vbuf, wT + (size_t)8192 * 2048, nullptr, nullptr, nullptr, nullptr, out);
}

// Round 5
// 692.713 us; speedup vs baseline: 1.1385x; 1.1385x over previous
//
#include <hip/hip_runtime.h>

typedef __bf16 bf16;
typedef __bf16 bf16x8 __attribute__((ext_vector_type(8)));
typedef __bf16 bf16x4 __attribute__((ext_vector_type(4)));
typedef float  f32x4  __attribute__((ext_vector_type(4)));

#define B_   2
#define S_   4096
#define HID_ 2048
#define H_   16
#define D_   128
#define C_   256
#define NC_  16
#define M_   (B_*S_)   // 8192 rows
#define K_   2048      // inner dim of both big GEMMs

typedef __attribute__((address_space(1))) const void gas_t;
typedef __attribute__((address_space(3))) void las_t;

// ---------------------------------------------------------------------------
// Fused convert: blocks [0,8192) do f32->bf16 of x (8 elems/thread);
// blocks [8192,28672) transpose-convert weights to bf16 [N][K]:
// rows 0..6143 = w_qkv cols, 6144..8191 = w_gate cols, 8192..10239 = w_out.
// ---------------------------------------------------------------------------
__global__ void cvt_kernel(const float* __restrict__ x,
                           const float* __restrict__ wqkv,
                           const float* __restrict__ wgate,
                           const float* __restrict__ wout,
                           bf16* __restrict__ xb, bf16* __restrict__ wT) {
    __shared__ float tile[32][33];
    int bid = blockIdx.x, tid = threadIdx.x;
    if (bid < 8192) {
        int idx = (bid * 256 + tid) * 8;
        float4 f0 = *(const float4*)(x + idx);
        float4 f1 = *(const float4*)(x + idx + 4);
        bf16x8 o;
        o[0] = (bf16)f0.x; o[1] = (bf16)f0.y; o[2] = (bf16)f0.z; o[3] = (bf16)f0.w;
        o[4] = (bf16)f1.x; o[5] = (bf16)f1.y; o[6] = (bf16)f1.z; o[7] = (bf16)f1.w;
        *(bf16x8*)(xb + idx) = o;
        return;
    }
    bid -= 8192;
    int k0 = (bid & 63) * 32, n0 = (bid >> 6) * 32;
    const float* src; int ld, col0;
    if (n0 < 6144)      { src = wqkv;  ld = 6144; col0 = n0; }
    else if (n0 < 8192) { src = wgate; ld = 2048; col0 = n0 - 6144; }
    else                { src = wout;  ld = 2048; col0 = n0 - 8192; }
    int tx = tid & 31, ty = tid >> 5;
#pragma unroll
    for (int i = 0; i < 4; i++) {
        int kk = ty + i * 8;
        tile[kk][tx] = src[(size_t)(k0 + kk) * ld + col0 + tx];
    }
    __syncthreads();
#pragma unroll
    for (int i = 0; i < 4; i++) {
        int nn = ty + i * 8;
        wT[(size_t)(n0 + nn) * K_ + k0 + tx] = (bf16)tile[tx][nn];
    }
}

// ---------------------------------------------------------------------------
// bf16 GEMM, C[M][N] = act( A[M][K] @ B[N][K]^T ).  128x128 tile, 4 waves
// (2x2 of 64x64), BK=64 (half the barriers of BK=32), global_load_lds w=16.
// LDS [row][64] XOR-swizzled: physical slot p holds logical colblock
// p ^ (row&7); fragment slot = (s*4+quad) ^ (l15&7) -> exactly 8 word
// accesses per bank per ds_read_b128 = phase minimum (conflict-free).
// MODE 0: N=8192, split output into q/k/v (silu) and gate (sigmoid), bf16.
// MODE 1: N=2048, plain f32 output to d_out.
// ---------------------------------------------------------------------------
template <int MODE>
__global__ __launch_bounds__(256) void gemm_kernel(
        const bf16* __restrict__ A, const bf16* __restrict__ Bm,
        bf16* __restrict__ qo, bf16* __restrict__ ko,
        bf16* __restrict__ vo, bf16* __restrict__ go,
        float* __restrict__ out) {
    __shared__ __align__(16) bf16 As[128 * 64];
    __shared__ __align__(16) bf16 Bs[128 * 64];
    const int m0 = blockIdx.x * 128, n0 = blockIdx.y * 128;
    const int tid = threadIdx.x, lane = tid & 63, wid = tid >> 6;
    const int quad = lane >> 4, l15 = lane & 15;
    const int i0w = (wid >> 1) * 64, j0w = (wid & 1) * 64;
    f32x4 acc[4][4] = {};
    // staging: thread tid -> row tid>>3 (32 rows/call), physical slot tid&7
    // holding logical colblock (tid&7) ^ (row&7).
    const int srow = tid >> 3;
    const int sl = (tid & 7) ^ (srow & 7);
    const bf16* Ag = A  + (size_t)(m0 + srow) * K_ + sl * 8;
    const bf16* Bg = Bm + (size_t)(n0 + srow) * K_ + sl * 8;
    bf16* AsDst = As + tid * 8;
    bf16* BsDst = Bs + tid * 8;
    const int xr = l15 & 7;   // fragment swizzle term (loop-invariant)

    for (int kb = 0; kb < K_; kb += 64) {
#pragma unroll
        for (int r = 0; r < 4; r++) {
            __builtin_amdgcn_global_load_lds((gas_t*)(Ag + kb + (size_t)r * 32 * K_),
                                             (las_t*)(AsDst + r * 2048), 16, 0, 0);
            __builtin_amdgcn_global_load_lds((gas_t*)(Bg + kb + (size_t)r * 32 * K_),
                                             (las_t*)(BsDst + r * 2048), 16, 0, 0);
        }
        __syncthreads();
        bf16x8 af[2][4], bfr[2][4];
#pragma unroll
        for (int s2 = 0; s2 < 2; s2++) {
            const int slot = (s2 * 4 + quad) ^ xr;
#pragma unroll
            for (int t = 0; t < 4; t++) {
                af[s2][t]  = *(const bf16x8*)&As[(i0w + t * 16 + l15) * 64 + slot * 8];
                bfr[s2][t] = *(const bf16x8*)&Bs[(j0w + t * 16 + l15) * 64 + slot * 8];
            }
        }
#pragma unroll
        for (int s2 = 0; s2 < 2; s2++)
#pragma unroll
            for (int ti = 0; ti < 4; ti++)
#pragma unroll
                for (int tj = 0; tj < 4; tj++)
                    acc[ti][tj] = __builtin_amdgcn_mfma_f32_16x16x32_bf16(
                        af[s2][ti], bfr[s2][tj], acc[ti][tj], 0, 0, 0);
        __syncthreads();
    }

    if (MODE == 0) {
        bf16* outb = (n0 < 2048) ? qo : (n0 < 4096) ? ko : (n0 < 6144) ? vo : go;
        const bool silu = (n0 < 6144);
        const int cb = n0 & 2047;
#pragma unroll
        for (int ti = 0; ti < 4; ti++)
#pragma unroll
            for (int tj = 0; tj < 4; tj++)
#pragma unroll
                for (int r = 0; r < 4; r++) {
                    int row = m0 + i0w + ti * 16 + quad * 4 + r;
                    int col = cb + j0w + tj * 16 + l15;
                    float xv = acc[ti][tj][r];
                    float sg = 1.f / (1.f + __expf(-xv));
                    float av = silu ? xv * sg : sg;
                    outb[(size_t)row * 2048 + col] = (bf16)av;
                }
    } else {
#pragma unroll
        for (int ti = 0; ti < 4; ti++)
#pragma unroll
            for (int tj = 0; tj < 4; tj++)
#pragma unroll
                for (int r = 0; r < 4; r++) {
                    int row = m0 + i0w + ti * 16 + quad * 4 + r;
                    int col = n0 + j0w + tj * 16 + l15;
                    out[(size_t)row * 2048 + col] = acc[ti][tj][r];
                }
    }
}

// ---------------------------------------------------------------------------
// Transpose k and v per (b,h): [S][D] -> [D][S]   (bf16, LDS 64x64 tiles)
// grid (S/64, D/64, 2*32): z = arr*32 + bh.
// The k copy (arr==0) is pre-scaled by k_decay[j] = exp(-s*(255 - j%256)),
// which depends only on tx -> one __expf per thread.  kT feeds only pass_a.
// ---------------------------------------------------------------------------
__global__ void transpose_kernel(const bf16* __restrict__ kin,
                                 const bf16* __restrict__ vin,
                                 const float* __restrict__ slopes,
                                 bf16* __restrict__ kT, bf16* __restrict__ vT) {
    __shared__ bf16 tile[64][65];
    int x0 = blockIdx.x * 64, d0 = blockIdx.y * 64;
    int z = blockIdx.z, arr = z >> 5, bh = z & 31, b = bh >> 4, h = bh & 15;
    const bf16* src = arr ? vin : kin;
    bf16* dst = arr ? vT : kT;
    int tx = threadIdx.x, ty = threadIdx.y;
    float fscale = 1.f;
    if (arr == 0)
        fscale = __expf(-slopes[h] * (float)(255 - ((x0 + tx) & 255)));
#pragma unroll
    for (int r = 0; r < 16; r++) {
        int lr = ty * 16 + r;
        tile[lr][tx] = src[(size_t)(b * S_ + x0 + lr) * 2048 + h * 128 + d0 + tx];
    }
    __syncthreads();
#pragma unroll
    for (int r = 0; r < 16; r++) {
        int lr = ty * 16 + r;
        dst[(size_t)(bh * 128 + d0 + lr) * S_ + x0 + tx] =
            (bf16)((float)tile[tx][lr] * fscale);
    }
}

// ---------------------------------------------------------------------------
// Pass A: per (chunk c, b, h) KV^T[e][d] = sum_j vT[e][j] * kT_scaled[d][j].
// M=N=128, K=256.  Pure load+MFMA (decay pre-folded into kT).
// ---------------------------------------------------------------------------
__global__ __launch_bounds__(256) void pass_a_kernel(
        const bf16* __restrict__ kT, const bf16* __restrict__ vT,
        bf16* __restrict__ KVT) {
    int c = blockIdx.x, bh = blockIdx.y;
    int tid = threadIdx.x, lane = tid & 63, wid = tid >> 6;
    int quad = lane >> 4, l15 = lane & 15;
    int e0 = (wid >> 1) * 64, d0 = (wid & 1) * 64;
    const bf16* vb = vT + (size_t)bh * 128 * S_ + c * 256;
    const bf16* kb = kT + (size_t)bh * 128 * S_ + c * 256;
    f32x4 acc[4][4] = {};
    for (int kbs = 0; kbs < 256; kbs += 32) {
        int j0 = kbs + quad * 8;
        bf16x8 af[4], bfr[4];
#pragma unroll
        for (int t = 0; t < 4; t++)
            af[t] = *(const bf16x8*)(vb + (size_t)(e0 + t * 16 + l15) * S_ + j0);
#pragma unroll
        for (int t = 0; t < 4; t++)
            bfr[t] = *(const bf16x8*)(kb + (size_t)(d0 + t * 16 + l15) * S_ + j0);
#pragma unroll
        for (int ti = 0; ti < 4; ti++)
#pragma unroll
            for (int tj = 0; tj < 4; tj++)
                acc[ti][tj] = __builtin_amdgcn_mfma_f32_16x16x32_bf16(
                    af[ti], bfr[tj], acc[ti][tj], 0, 0, 0);
    }
    size_t base = ((size_t)c * 32 + bh) * 16384;
#pragma unroll
    for (int ti = 0; ti < 4; ti++)
#pragma unroll
        for (int tj = 0; tj < 4; tj++)
#pragma unroll
            for (int r = 0; r < 4; r++) {
                int e = e0 + ti * 16 + quad * 4 + r, d = d0 + tj * 16 + l15;
                KVT[base + (size_t)e * 128 + d] = (bf16)acc[ti][tj][r];
            }
}

// ---------------------------------------------------------------------------
// Pass B: decayed prefix scan of KV^T over chunks; stT[c] = state BEFORE c.
// ---------------------------------------------------------------------------
__global__ void scan_kernel(const bf16* __restrict__ KVT,
                            const float* __restrict__ slopes,
                            bf16* __restrict__ stT) {
    int slice = blockIdx.x, bh = blockIdx.y;
    float s = slopes[bh & 15];
    float bd = __expf(-s * 256.f);
    size_t off = (size_t)slice * 1024 + threadIdx.x * 4;
    float kv0 = 0.f, kv1 = 0.f, kv2 = 0.f, kv3 = 0.f;
    for (int c = 0; c < 16; c++) {
        size_t idx = ((size_t)c * 32 + bh) * 16384 + off;
        bf16x4 st;
        st[0] = (bf16)kv0; st[1] = (bf16)kv1; st[2] = (bf16)kv2; st[3] = (bf16)kv3;
        *(bf16x4*)(stT + idx) = st;
        bf16x4 kvc = *(const bf16x4*)(KVT + idx);
        kv0 = bd * kv0 + (float)kvc[0];
        kv1 = bd * kv1 + (float)kvc[1];
        kv2 = bd * kv2 + (float)kvc[2];
        kv3 = bd * kv3 + (float)kvc[3];
    }
}

// ---------------------------------------------------------------------------
// Pass C (round-3 known-good shape): o[i][e] = sum_j decay(i,j)(q_i.k_j)v[j][e]
// + qd[i]*(q_i @ state), then * sigmoid gate, bf16 store.  Wave w owns rows
// i0=w*64 x 128 e-cols.  P round-trips through wave-private LDS rows.
// ---------------------------------------------------------------------------
__global__ __launch_bounds__(256) void pass_c_kernel(
        const bf16* __restrict__ q, const bf16* __restrict__ kk,
        const bf16* __restrict__ vT, const bf16* __restrict__ stT,
        const bf16* __restrict__ gate, const float* __restrict__ slopes,
        bf16* __restrict__ og) {
    __shared__ __align__(16) bf16 P[256 * 72];
    __shared__ float dtab[257];
    int c = blockIdx.x, bh = blockIdx.y, b = bh >> 4, h = bh & 15;
    int tid = threadIdx.x, lane = tid & 63, wid = tid >> 6;
    int quad = lane >> 4, l15 = lane & 15;
    int i0 = wid * 64;
    float s = slopes[h];
    dtab[tid] = __expf(-s * (float)tid);
    if (tid == 0) dtab[256] = __expf(-s * 256.f);
    __syncthreads();
    const bf16* qb = q  + ((size_t)(b * S_ + c * 256)) * 2048 + h * 128;
    const bf16* kb = kk + ((size_t)(b * S_ + c * 256)) * 2048 + h * 128;
    const bf16* vb = vT + (size_t)bh * 128 * S_ + c * 256;
    const bf16* st = stT + ((size_t)c * 32 + bh) * 16384;
    f32x4 acc[4][8] = {};

    // inter-chunk: (q * q_decay) @ stateT rows, K=128
    for (int kbs = 0; kbs < 128; kbs += 32) {
        bf16x8 af[4];
#pragma unroll
        for (int t = 0; t < 4; t++) {
            int i = i0 + t * 16 + l15;
            float qd = dtab[i + 1];
            bf16x8 raw = *(const bf16x8*)(qb + (size_t)i * 2048 + kbs + quad * 8);
            bf16x8 sc;
#pragma unroll
            for (int jj = 0; jj < 8; jj++) sc[jj] = (bf16)((float)raw[jj] * qd);
            af[t] = sc;
        }
#pragma unroll
        for (int te = 0; te < 8; te++) {
            bf16x8 bfr = *(const bf16x8*)(st + (size_t)(te * 16 + l15) * 128 + kbs + quad * 8);
#pragma unroll
            for (int t = 0; t < 4; t++)
                acc[t][te] = __builtin_amdgcn_mfma_f32_16x16x32_bf16(
                    af[t], bfr, acc[t][te], 0, 0, 0);
        }
    }

    // intra-chunk, 4 j-tiles of 64
    for (int jt = 0; jt < 4; jt++) {
        f32x4 sacc[4][4] = {};
        for (int kbs = 0; kbs < 128; kbs += 32) {
            bf16x8 af[4], bkr[4];
#pragma unroll
            for (int t = 0; t < 4; t++)
                af[t] = *(const bf16x8*)(qb + (size_t)(i0 + t * 16 + l15) * 2048 + kbs + quad * 8);
#pragma unroll
            for (int t = 0; t < 4; t++)
                bkr[t] = *(const bf16x8*)(kb + (size_t)(jt * 64 + t * 16 + l15) * 2048 + kbs + quad * 8);
#pragma unroll
            for (int ti = 0; ti < 4; ti++)
#pragma unroll
                for (int tj = 0; tj < 4; tj++)
                    sacc[ti][tj] = __builtin_amdgcn_mfma_f32_16x16x32_bf16(
                        af[ti], bkr[tj], sacc[ti][tj], 0, 0, 0);
        }
        // causal decay, write P rows (wave-private)
#pragma unroll
        for (int ti = 0; ti < 4; ti++)
#pragma unroll
            for (int tj = 0; tj < 4; tj++)
#pragma unroll
                for (int r = 0; r < 4; r++) {
                    int i = i0 + ti * 16 + quad * 4 + r;
                    int j = jt * 64 + tj * 16 + l15;
                    int diff = i - j;
                    float pv = (diff >= 0) ? sacc[ti][tj][r] * dtab[diff] : 0.f;
                    P[i * 72 + tj * 16 + l15] = (bf16)pv;
                }
        // o += P @ vT rows, K=64
#pragma unroll
        for (int k2 = 0; k2 < 64; k2 += 32) {
            bf16x8 af[4];
#pragma unroll
            for (int t = 0; t < 4; t++)
                af[t] = *(const bf16x8*)&P[(i0 + t * 16 + l15) * 72 + k2 + quad * 8];
#pragma unroll
            for (int te = 0; te < 8; te++) {
                bf16x8 bfr = *(const bf16x8*)(vb + (size_t)(te * 16 + l15) * S_ + jt * 64 + k2 + quad * 8);
#pragma unroll
                for (int t = 0; t < 4; t++)
                    acc[t][te] = __builtin_amdgcn_mfma_f32_16x16x32_bf16(
                        af[t], bfr, acc[t][te], 0, 0, 0);
            }
        }
    }

    // epilogue: multiply gate, store bf16
    const bf16* gb = gate + ((size_t)(b * S_ + c * 256)) * 2048 + h * 128;
    bf16* ob = og + ((size_t)(b * S_ + c * 256)) * 2048 + h * 128;
#pragma unroll
    for (int ti = 0; ti < 4; ti++)
#pragma unroll
        for (int te = 0; te < 8; te++)
#pragma unroll
            for (int r = 0; r < 4; r++) {
                int i = i0 + ti * 16 + quad * 4 + r;
                int e = te * 16 + l15;
                float gv = (float)gb[(size_t)i * 2048 + e];
                ob[(size_t)i * 2048 + e] = (bf16)(acc[ti][te][r] * gv);
            }
}

// ---------------------------------------------------------------------------
// Workspace budget (d_ws): 200 MiB.  wT 40 + xb 32 + q/k/v/g 128.
// kT aliases xb (dead after GEMM1).  vT/KVT/stT live in d_out (64 MiB f32),
// all dead before GEMM2 overwrites d_out.
// ---------------------------------------------------------------------------
extern "C" void kernel_launch(void* const* d_in, const int* in_sizes, int n_in,
                              void* d_out, int out_size, void* d_ws, size_t ws_size,
                              hipStream_t stream) {
    const float* x      = (const float*)d_in[0];
    const float* wqkv   = (const float*)d_in[1];
    const float* wgate  = (const float*)d_in[2];
    const float* wout   = (const float*)d_in[3];
    const float* slopes = (const float*)d_in[4];
    float* out = (float*)d_out;

    bf16* wT   = (bf16*)d_ws;                       // [10240][2048]  40 MiB
    bf16* xb   = wT   + (size_t)10240 * 2048;       // [8192][2048]   32 MiB
    bf16* qb   = xb   + (size_t)8192 * 2048;        // 32 MiB
    bf16* kbuf = qb   + (size_t)8192 * 2048;        // 32 MiB
    bf16* vbuf = kbuf + (size_t)8192 * 2048;        // 32 MiB (reused: gated attn)
    bf16* gbuf = vbuf + (size_t)8192 * 2048;        // 32 MiB
    bf16* kT   = xb;                                // alias: xb dead after GEMM1
    bf16* vT   = (bf16*)d_out;                      // [32][128][4096] 32 MiB
    bf16* KVT  = vT + (size_t)32 * 128 * 4096;      // [16][32][128][128] 16 MiB
    bf16* stT  = KVT + (size_t)16 * 32 * 16384;     // 16 MiB  (total = 64 MiB)

    cvt_kernel<<<dim3(28672), dim3(256), 0, stream>>>(x, wqkv, wgate, wout, xb, wT);
    gemm_kernel<0><<<dim3(64, 64), dim3(256), 0, stream>>>(
        xb, wT, qb, kbuf, vbuf, gbuf, (float*)nullptr);
    transpose_kernel<<<dim3(64, 2, 64), dim3(64, 4), 0, stream>>>(
        kbuf, vbuf, slopes, kT, vT);
    pass_a_kernel<<<dim3(16, 32), dim3(256), 0, stream>>>(kT, vT, KVT);
    scan_kernel<<<dim3(16, 32), dim3(256), 0, stream>>>(KVT, slopes, stT);
    pass_c_kernel<<<dim3(16, 32), dim3(256), 0, stream>>>(
        qb, kbuf, vT, stT, gbuf, slopes, vbuf);
    gemm_kernel<1><<<dim3(64, 16), dim3(256), 0, stream>>>(
        vbuf, wT + (size_t)8192 * 2048, nullptr, nullptr, nullptr, nullptr, out);
}

// Round 6
// 690.238 us; speedup vs baseline: 1.1426x; 1.0036x over previous
//
#include <hip/hip_runtime.h>

typedef __bf16 bf16;
typedef __bf16 bf16x8 __attribute__((ext_vector_type(8)));
typedef __bf16 bf16x4 __attribute__((ext_vector_type(4)));
typedef float  f32x4  __attribute__((ext_vector_type(4)));

#define B_   2
#define S_   4096
#define HID_ 2048
#define H_   16
#define D_   128
#define C_   256
#define NC_  16
#define M_   (B_*S_)   // 8192 rows
#define K_   2048      // inner dim of both big GEMMs

typedef __attribute__((address_space(1))) const void gas_t;
typedef __attribute__((address_space(3))) void las_t;

// ---------------------------------------------------------------------------
// Fused convert: blocks [0,8192) do f32->bf16 of x (8 elems/thread);
// blocks [8192,28672) transpose-convert weights to bf16 [N][K]:
// rows 0..6143 = w_qkv cols, 6144..8191 = w_gate cols, 8192..10239 = w_out.
// ---------------------------------------------------------------------------
__global__ void cvt_kernel(const float* __restrict__ x,
                           const float* __restrict__ wqkv,
                           const float* __restrict__ wgate,
                           const float* __restrict__ wout,
                           bf16* __restrict__ xb, bf16* __restrict__ wT) {
    __shared__ float tile[32][33];
    int bid = blockIdx.x, tid = threadIdx.x;
    if (bid < 8192) {
        int idx = (bid * 256 + tid) * 8;
        float4 f0 = *(const float4*)(x + idx);
        float4 f1 = *(const float4*)(x + idx + 4);
        bf16x8 o;
        o[0] = (bf16)f0.x; o[1] = (bf16)f0.y; o[2] = (bf16)f0.z; o[3] = (bf16)f0.w;
        o[4] = (bf16)f1.x; o[5] = (bf16)f1.y; o[6] = (bf16)f1.z; o[7] = (bf16)f1.w;
        *(bf16x8*)(xb + idx) = o;
        return;
    }
    bid -= 8192;
    int k0 = (bid & 63) * 32, n0 = (bid >> 6) * 32;
    const float* src; int ld, col0;
    if (n0 < 6144)      { src = wqkv;  ld = 6144; col0 = n0; }
    else if (n0 < 8192) { src = wgate; ld = 2048; col0 = n0 - 6144; }
    else                { src = wout;  ld = 2048; col0 = n0 - 8192; }
    int tx = tid & 31, ty = tid >> 5;
#pragma unroll
    for (int i = 0; i < 4; i++) {
        int kk = ty + i * 8;
        tile[kk][tx] = src[(size_t)(k0 + kk) * ld + col0 + tx];
    }
    __syncthreads();
#pragma unroll
    for (int i = 0; i < 4; i++) {
        int nn = ty + i * 8;
        wT[(size_t)(n0 + nn) * K_ + k0 + tx] = (bf16)tile[tx][nn];
    }
}

// ---------------------------------------------------------------------------
// bf16 GEMM, C[M][N] = act( A[M][K] @ B[N][K]^T ).  128x128 tile, 4 waves
// (2x2 of 64x64), BK=64 (half the barriers of BK=32), global_load_lds w=16.
// LDS [row][64] XOR-swizzled: physical slot p holds logical colblock
// p ^ (row&7); fragment slot = (s*4+quad) ^ (l15&7) -> conflict-free.
// MODE 0: N=8192, split output into q/k/v (silu) and gate (sigmoid), bf16.
// MODE 1: N=2048, plain f32 output to d_out.
// ---------------------------------------------------------------------------
template <int MODE>
__global__ __launch_bounds__(256) void gemm_kernel(
        const bf16* __restrict__ A, const bf16* __restrict__ Bm,
        bf16* __restrict__ qo, bf16* __restrict__ ko,
        bf16* __restrict__ vo, bf16* __restrict__ go,
        float* __restrict__ out) {
    __shared__ __align__(16) bf16 As[128 * 64];
    __shared__ __align__(16) bf16 Bs[128 * 64];
    const int m0 = blockIdx.x * 128, n0 = blockIdx.y * 128;
    const int tid = threadIdx.x, lane = tid & 63, wid = tid >> 6;
    const int quad = lane >> 4, l15 = lane & 15;
    const int i0w = (wid >> 1) * 64, j0w = (wid & 1) * 64;
    f32x4 acc[4][4] = {};
    const int srow = tid >> 3;
    const int sl = (tid & 7) ^ (srow & 7);
    const bf16* Ag = A  + (size_t)(m0 + srow) * K_ + sl * 8;
    const bf16* Bg = Bm + (size_t)(n0 + srow) * K_ + sl * 8;
    bf16* AsDst = As + tid * 8;
    bf16* BsDst = Bs + tid * 8;
    const int xr = l15 & 7;

    for (int kb = 0; kb < K_; kb += 64) {
#pragma unroll
        for (int r = 0; r < 4; r++) {
            __builtin_amdgcn_global_load_lds((gas_t*)(Ag + kb + (size_t)r * 32 * K_),
                                             (las_t*)(AsDst + r * 2048), 16, 0, 0);
            __builtin_amdgcn_global_load_lds((gas_t*)(Bg + kb + (size_t)r * 32 * K_),
                                             (las_t*)(BsDst + r * 2048), 16, 0, 0);
        }
        __syncthreads();
        bf16x8 af[2][4], bfr[2][4];
#pragma unroll
        for (int s2 = 0; s2 < 2; s2++) {
            const int slot = (s2 * 4 + quad) ^ xr;
#pragma unroll
            for (int t = 0; t < 4; t++) {
                af[s2][t]  = *(const bf16x8*)&As[(i0w + t * 16 + l15) * 64 + slot * 8];
                bfr[s2][t] = *(const bf16x8*)&Bs[(j0w + t * 16 + l15) * 64 + slot * 8];
            }
        }
#pragma unroll
        for (int s2 = 0; s2 < 2; s2++)
#pragma unroll
            for (int ti = 0; ti < 4; ti++)
#pragma unroll
                for (int tj = 0; tj < 4; tj++)
                    acc[ti][tj] = __builtin_amdgcn_mfma_f32_16x16x32_bf16(
                        af[s2][ti], bfr[s2][tj], acc[ti][tj], 0, 0, 0);
        __syncthreads();
    }

    if (MODE == 0) {
        bf16* outb = (n0 < 2048) ? qo : (n0 < 4096) ? ko : (n0 < 6144) ? vo : go;
        const bool silu = (n0 < 6144);
        const int cb = n0 & 2047;
#pragma unroll
        for (int ti = 0; ti < 4; ti++)
#pragma unroll
            for (int tj = 0; tj < 4; tj++)
#pragma unroll
                for (int r = 0; r < 4; r++) {
                    int row = m0 + i0w + ti * 16 + quad * 4 + r;
                    int col = cb + j0w + tj * 16 + l15;
                    float xv = acc[ti][tj][r];
                    float sg = 1.f / (1.f + __expf(-xv));
                    float av = silu ? xv * sg : sg;
                    outb[(size_t)row * 2048 + col] = (bf16)av;
                }
    } else {
#pragma unroll
        for (int ti = 0; ti < 4; ti++)
#pragma unroll
            for (int tj = 0; tj < 4; tj++)
#pragma unroll
                for (int r = 0; r < 4; r++) {
                    int row = m0 + i0w + ti * 16 + quad * 4 + r;
                    int col = n0 + j0w + tj * 16 + l15;
                    out[(size_t)row * 2048 + col] = acc[ti][tj][r];
                }
    }
}

// ---------------------------------------------------------------------------
// Transpose k and v per (b,h): [S][D] -> [D][S]   (bf16, LDS 64x64 tiles)
// grid (S/64, D/64, 2*32): z = arr*32 + bh.
// The k copy (arr==0) is pre-scaled by k_decay[j] = exp(-s*(255 - j%256)).
// ---------------------------------------------------------------------------
__global__ void transpose_kernel(const bf16* __restrict__ kin,
                                 const bf16* __restrict__ vin,
                                 const float* __restrict__ slopes,
                                 bf16* __restrict__ kT, bf16* __restrict__ vT) {
    __shared__ bf16 tile[64][65];
    int x0 = blockIdx.x * 64, d0 = blockIdx.y * 64;
    int z = blockIdx.z, arr = z >> 5, bh = z & 31, b = bh >> 4, h = bh & 15;
    const bf16* src = arr ? vin : kin;
    bf16* dst = arr ? vT : kT;
    int tx = threadIdx.x, ty = threadIdx.y;
    float fscale = 1.f;
    if (arr == 0)
        fscale = __expf(-slopes[h] * (float)(255 - ((x0 + tx) & 255)));
#pragma unroll
    for (int r = 0; r < 16; r++) {
        int lr = ty * 16 + r;
        tile[lr][tx] = src[(size_t)(b * S_ + x0 + lr) * 2048 + h * 128 + d0 + tx];
    }
    __syncthreads();
#pragma unroll
    for (int r = 0; r < 16; r++) {
        int lr = ty * 16 + r;
        dst[(size_t)(bh * 128 + d0 + lr) * S_ + x0 + tx] =
            (bf16)((float)tile[tx][lr] * fscale);
    }
}

// ---------------------------------------------------------------------------
// Pass A: per (chunk c, b, h) KV^T[e][d] = sum_j vT[e][j] * kT_scaled[d][j].
// M=N=128, K=256.  Pure load+MFMA (decay pre-folded into kT).
// ---------------------------------------------------------------------------
__global__ __launch_bounds__(256) void pass_a_kernel(
        const bf16* __restrict__ kT, const bf16* __restrict__ vT,
        bf16* __restrict__ KVT) {
    int c = blockIdx.x, bh = blockIdx.y;
    int tid = threadIdx.x, lane = tid & 63, wid = tid >> 6;
    int quad = lane >> 4, l15 = lane & 15;
    int e0 = (wid >> 1) * 64, d0 = (wid & 1) * 64;
    const bf16* vb = vT + (size_t)bh * 128 * S_ + c * 256;
    const bf16* kb = kT + (size_t)bh * 128 * S_ + c * 256;
    f32x4 acc[4][4] = {};
    for (int kbs = 0; kbs < 256; kbs += 32) {
        int j0 = kbs + quad * 8;
        bf16x8 af[4], bfr[4];
#pragma unroll
        for (int t = 0; t < 4; t++)
            af[t] = *(const bf16x8*)(vb + (size_t)(e0 + t * 16 + l15) * S_ + j0);
#pragma unroll
        for (int t = 0; t < 4; t++)
            bfr[t] = *(const bf16x8*)(kb + (size_t)(d0 + t * 16 + l15) * S_ + j0);
#pragma unroll
        for (int ti = 0; ti < 4; ti++)
#pragma unroll
            for (int tj = 0; tj < 4; tj++)
                acc[ti][tj] = __builtin_amdgcn_mfma_f32_16x16x32_bf16(
                    af[ti], bfr[tj], acc[ti][tj], 0, 0, 0);
    }
    size_t base = ((size_t)c * 32 + bh) * 16384;
#pragma unroll
    for (int ti = 0; ti < 4; ti++)
#pragma unroll
        for (int tj = 0; tj < 4; tj++)
#pragma unroll
            for (int r = 0; r < 4; r++) {
                int e = e0 + ti * 16 + quad * 4 + r, d = d0 + tj * 16 + l15;
                KVT[base + (size_t)e * 128 + d] = (bf16)acc[ti][tj][r];
            }
}

// ---------------------------------------------------------------------------
// Pass B: decayed prefix scan of KV^T over chunks; stT[c] = state BEFORE c.
// ---------------------------------------------------------------------------
__global__ void scan_kernel(const bf16* __restrict__ KVT,
                            const float* __restrict__ slopes,
                            bf16* __restrict__ stT) {
    int slice = blockIdx.x, bh = blockIdx.y;
    float s = slopes[bh & 15];
    float bd = __expf(-s * 256.f);
    size_t off = (size_t)slice * 1024 + threadIdx.x * 4;
    float kv0 = 0.f, kv1 = 0.f, kv2 = 0.f, kv3 = 0.f;
    for (int c = 0; c < 16; c++) {
        size_t idx = ((size_t)c * 32 + bh) * 16384 + off;
        bf16x4 st;
        st[0] = (bf16)kv0; st[1] = (bf16)kv1; st[2] = (bf16)kv2; st[3] = (bf16)kv3;
        *(bf16x4*)(stT + idx) = st;
        bf16x4 kvc = *(const bf16x4*)(KVT + idx);
        kv0 = bd * kv0 + (float)kvc[0];
        kv1 = bd * kv1 + (float)kvc[1];
        kv2 = bd * kv2 + (float)kvc[2];
        kv3 = bd * kv3 + (float)kvc[3];
    }
}

// ---------------------------------------------------------------------------
// Pass C (round-3 shape + wave-causal skip): wave w owns rows i0=w*64, so
// j-tiles jt>w are fully masked -> loop jt<=wid only (removes 37.5% of the
// intra-chunk MFMA work).  Inter-chunk q-decay applied as accumulator
// post-scale instead of per-K-step A-fragment repack.
// ---------------------------------------------------------------------------
__global__ __launch_bounds__(256) void pass_c_kernel(
        const bf16* __restrict__ q, const bf16* __restrict__ kk,
        const bf16* __restrict__ vT, const bf16* __restrict__ stT,
        const bf16* __restrict__ gate, const float* __restrict__ slopes,
        bf16* __restrict__ og) {
    __shared__ __align__(16) bf16 P[256 * 72];
    __shared__ float dtab[257];
    int c = blockIdx.x, bh = blockIdx.y, b = bh >> 4, h = bh & 15;
    int tid = threadIdx.x, lane = tid & 63, wid = tid >> 6;
    int quad = lane >> 4, l15 = lane & 15;
    int i0 = wid * 64;
    float s = slopes[h];
    dtab[tid] = __expf(-s * (float)tid);
    if (tid == 0) dtab[256] = __expf(-s * 256.f);
    __syncthreads();
    const bf16* qb = q  + ((size_t)(b * S_ + c * 256)) * 2048 + h * 128;
    const bf16* kb = kk + ((size_t)(b * S_ + c * 256)) * 2048 + h * 128;
    const bf16* vb = vT + (size_t)bh * 128 * S_ + c * 256;
    const bf16* st = stT + ((size_t)c * 32 + bh) * 16384;
    f32x4 acc[4][8] = {};

    // inter-chunk: q @ stateT rows, K=128 (decay applied after)
    for (int kbs = 0; kbs < 128; kbs += 32) {
        bf16x8 af[4];
#pragma unroll
        for (int t = 0; t < 4; t++)
            af[t] = *(const bf16x8*)(qb + (size_t)(i0 + t * 16 + l15) * 2048 + kbs + quad * 8);
#pragma unroll
        for (int te = 0; te < 8; te++) {
            bf16x8 bfr = *(const bf16x8*)(st + (size_t)(te * 16 + l15) * 128 + kbs + quad * 8);
#pragma unroll
            for (int t = 0; t < 4; t++)
                acc[t][te] = __builtin_amdgcn_mfma_f32_16x16x32_bf16(
                    af[t], bfr, acc[t][te], 0, 0, 0);
        }
    }
    // scale inter result by q_decay(row) = dtab[i+1]
#pragma unroll
    for (int t = 0; t < 4; t++) {
        float qd[4];
#pragma unroll
        for (int r = 0; r < 4; r++) qd[r] = dtab[i0 + t * 16 + quad * 4 + r + 1];
#pragma unroll
        for (int te = 0; te < 8; te++)
#pragma unroll
            for (int r = 0; r < 4; r++) acc[t][te][r] *= qd[r];
    }

    // intra-chunk: only causal j-tiles (jt <= wid)
    for (int jt = 0; jt <= wid; jt++) {
        f32x4 sacc[4][4] = {};
        for (int kbs = 0; kbs < 128; kbs += 32) {
            bf16x8 af[4], bkr[4];
#pragma unroll
            for (int t = 0; t < 4; t++)
                af[t] = *(const bf16x8*)(qb + (size_t)(i0 + t * 16 + l15) * 2048 + kbs + quad * 8);
#pragma unroll
            for (int t = 0; t < 4; t++)
                bkr[t] = *(const bf16x8*)(kb + (size_t)(jt * 64 + t * 16 + l15) * 2048 + kbs + quad * 8);
#pragma unroll
            for (int ti = 0; ti < 4; ti++)
#pragma unroll
                for (int tj = 0; tj < 4; tj++)
                    sacc[ti][tj] = __builtin_amdgcn_mfma_f32_16x16x32_bf16(
                        af[ti], bkr[tj], sacc[ti][tj], 0, 0, 0);
        }
        // causal decay, write P rows (wave-private)
#pragma unroll
        for (int ti = 0; ti < 4; ti++)
#pragma unroll
            for (int tj = 0; tj < 4; tj++)
#pragma unroll
                for (int r = 0; r < 4; r++) {
                    int i = i0 + ti * 16 + quad * 4 + r;
                    int j = jt * 64 + tj * 16 + l15;
                    int diff = i - j;
                    float pv = (diff >= 0) ? sacc[ti][tj][r] * dtab[diff] : 0.f;
                    P[i * 72 + tj * 16 + l15] = (bf16)pv;
                }
        // o += P @ vT rows, K=64
#pragma unroll
        for (int k2 = 0; k2 < 64; k2 += 32) {
            bf16x8 af[4];
#pragma unroll
            for (int t = 0; t < 4; t++)
                af[t] = *(const bf16x8*)&P[(i0 + t * 16 + l15) * 72 + k2 + quad * 8];
#pragma unroll
            for (int te = 0; te < 8; te++) {
                bf16x8 bfr = *(const bf16x8*)(vb + (size_t)(te * 16 + l15) * S_ + jt * 64 + k2 + quad * 8);
#pragma unroll
                for (int t = 0; t < 4; t++)
                    acc[t][te] = __builtin_amdgcn_mfma_f32_16x16x32_bf16(
                        af[t], bfr, acc[t][te], 0, 0, 0);
            }
        }
    }

    // epilogue: multiply gate, store bf16
    const bf16* gb = gate + ((size_t)(b * S_ + c * 256)) * 2048 + h * 128;
    bf16* ob = og + ((size_t)(b * S_ + c * 256)) * 2048 + h * 128;
#pragma unroll
    for (int ti = 0; ti < 4; ti++)
#pragma unroll
        for (int te = 0; te < 8; te++)
#pragma unroll
            for (int r = 0; r < 4; r++) {
                int i = i0 + ti * 16 + quad * 4 + r;
                int e = te * 16 + l15;
                float gv = (float)gb[(size_t)i * 2048 + e];
                ob[(size_t)i * 2048 + e] = (bf16)(acc[ti][te][r] * gv);
            }
}

// ---------------------------------------------------------------------------
// Workspace budget (d_ws): 200 MiB.  wT 40 + xb 32 + q/k/v/g 128.
// kT aliases xb (dead after GEMM1).  vT/KVT/stT live in d_out (64 MiB f32),
// all dead before GEMM2 overwrites d_out.
// ---------------------------------------------------------------------------
extern "C" void kernel_launch(void* const* d_in, const int* in_sizes, int n_in,
                              void* d_out, int out_size, void* d_ws, size_t ws_size,
                              hipStream_t stream) {
    const float* x      = (const float*)d_in[0];
    const float* wqkv   = (const float*)d_in[1];
    const float* wgate  = (const float*)d_in[2];
    const float* wout   = (const float*)d_in[3];
    const float* slopes = (const float*)d_in[4];
    float* out = (float*)d_out;

    bf16* wT   = (bf16*)d_ws;                       // [10240][2048]  40 MiB
    bf16* xb   = wT   + (size_t)10240 * 2048;       // [8192][2048]   32 MiB
    bf16* qb   = xb   + (size_t)8192 * 2048;        // 32 MiB
    bf16* kbuf = qb   + (size_t)8192 * 2048;        // 32 MiB
    bf16* vbuf = kbuf + (size_t)8192 * 2048;        // 32 MiB (reused: gated attn)
    bf16* gbuf = vbuf + (size_t)8192 * 2048;        // 32 MiB
    bf16* kT   = xb;                                // alias: xb dead after GEMM1
    bf16* vT   = (bf16*)d_out;                      // [32][128][4096] 32 MiB
    bf16* KVT  = vT + (size_t)32 * 128 * 4096;      // [16][32][128][128] 16 MiB
    bf16* stT  = KVT + (size_t)16 * 32 * 16384;     // 16 MiB  (total = 64 MiB)

    cvt_kernel<<<dim3(28672), dim3(256), 0, stream>>>(x, wqkv, wgate, wout, xb, wT);
    gemm_kernel<0><<<dim3(64, 64), dim3(256), 0, stream>>>(
        xb, wT, qb, kbuf, vbuf, gbuf, (float*)nullptr);
    transpose_kernel<<<dim3(64, 2, 64), dim3(64, 4), 0, stream>>>(
        kbuf, vbuf, slopes, kT, vT);
    pass_a_kernel<<<dim3(16, 32), dim3(256), 0, stream>>>(kT, vT, KVT);
    scan_kernel<<<dim3(16, 32), dim3(256), 0, stream>>>(KVT, slopes, stT);
    pass_c_kernel<<<dim3(16, 32), dim3(256), 0, stream>>>(
        qb, kbuf, vT, stT, gbuf, slopes, vbuf);
    gemm_kernel<1><<<dim3(64, 16), dim3(256), 0, stream>>>(
        vbuf, wT + (size_t)8192 * 2048, nullptr, nullptr, nullptr, nullptr, out);
}